// Round 1
// baseline (134.405 us; speedup 1.0000x reference)
//
#include <hip/hip_runtime.h>
#include <hip/hip_bf16.h>

// Problem constants (B=16, Q=900, C=512, T=40, L=91)
#define BQ   14400      // B*Q rows
#define BT   640        // B*T cols
#define CD   512        // class dim (K of the GEMM)
#define LD   91
#define TD   40

typedef __attribute__((ext_vector_type(8))) short short8;
typedef __attribute__((ext_vector_type(4))) float f32x4;

// ---------------------------------------------------------------------------
// Pass 1: lm[j][c] = label_maps[b, class_labels[j], c] / rowsum  (bf16)
// ---------------------------------------------------------------------------
__global__ __launch_bounds__(256) void build_lm_kernel(
    const float* __restrict__ label_maps,   // [16][91][512]
    const int* __restrict__ class_labels,   // [640]
    __hip_bfloat16* __restrict__ lm)        // [640][512]
{
    int j = blockIdx.x;                 // 0..639
    int b = j / TD;
    int cls = class_labels[j];
    const float* src = label_maps + ((size_t)b * LD + cls) * CD;
    int t = threadIdx.x;                // 256 threads, 2 elems each
    float v0 = src[t];
    float v1 = src[t + 256];
    float s = v0 + v1;
    #pragma unroll
    for (int off = 32; off >= 1; off >>= 1) s += __shfl_down(s, off, 64);
    __shared__ float red[4];
    if ((t & 63) == 0) red[t >> 6] = s;
    __syncthreads();
    float inv = 1.0f / (red[0] + red[1] + red[2] + red[3]);
    lm[(size_t)j * CD + t]       = __float2bfloat16(v0 * inv);
    lm[(size_t)j * CD + t + 256] = __float2bfloat16(v1 * inv);
}

// ---------------------------------------------------------------------------
// Pass 2: F[i][c] = pos_cost - neg_cost from logits (bf16), elementwise
// ---------------------------------------------------------------------------
__global__ __launch_bounds__(256) void build_focal_kernel(
    const float* __restrict__ logits,       // [14400*512]
    __hip_bfloat16* __restrict__ F)         // [14400*512]
{
    size_t i = ((size_t)blockIdx.x * 256 + threadIdx.x) * 4;
    float4 x = *(const float4*)(logits + i);
    float xs[4] = {x.x, x.y, x.z, x.w};
    union { __hip_bfloat16 h[4]; uint2 u; } pk;
    #pragma unroll
    for (int k = 0; k < 4; ++k) {
        float p = 1.0f / (1.0f + __expf(-xs[k]));
        float pos = 0.25f * (1.0f - p) * (1.0f - p) * (-__logf(p + 1e-8f));
        float neg = 0.75f * p * p * (-__logf(1.0f - p + 1e-8f));
        pk.h[k] = __float2bfloat16(pos - neg);
    }
    *(uint2*)(F + i) = pk.u;
}

// ---------------------------------------------------------------------------
// Pass 3: cost GEMM (F @ lm^T) via bf16 MFMA + fused bbox/GIoU epilogue
//   tile 64x64, 4 waves (2x2), BK=32, single-buffered LDS, padded rows
// ---------------------------------------------------------------------------
__global__ __launch_bounds__(256) void cost_gemm_kernel(
    const __hip_bfloat16* __restrict__ F,    // [14400][512]
    const __hip_bfloat16* __restrict__ lm,   // [640][512]
    const float* __restrict__ pred_boxes,    // [14400][4] cxcywh
    const float* __restrict__ tboxes,        // [640][4]   cxcywh
    float* __restrict__ out)                 // [14400][640]
{
    // +8 short pad -> 80 B row stride (5*16 B): 16B-aligned b128, ~2-way banks
    __shared__ short As[64][40];
    __shared__ short Bs[64][40];
    __shared__ float pB[64][4];
    __shared__ float tB[64][4];

    int m0 = blockIdx.x * 64;
    int n0 = blockIdx.y * 64;
    int t  = threadIdx.x;

    // stage boxes for this block's rows/cols
    {
        int r = t >> 2, c = t & 3;
        pB[r][c] = pred_boxes[(size_t)(m0 + r) * 4 + c];
        tB[r][c] = tboxes[(size_t)(n0 + r) * 4 + c];
    }

    int lane = t & 63;
    int w    = t >> 6;
    int wr   = w >> 1, wc = w & 1;      // wave 2x2 grid, each 32x32 out
    int lrow = lane & 15;               // MFMA row/col within 16
    int kg   = lane >> 4;               // k-group 0..3

    f32x4 acc[2][2] = {};

    int sr = t >> 2;                    // staging row 0..63
    int sk = (t & 3) * 8;               // staging k-offset (8 bf16 = 16 B)
    const __hip_bfloat16* gA = F  + (size_t)(m0 + sr) * CD + sk;
    const __hip_bfloat16* gB = lm + (size_t)(n0 + sr) * CD + sk;

    for (int kk = 0; kk < CD; kk += 32) {
        uint4 av = *(const uint4*)(gA + kk);
        uint4 bv = *(const uint4*)(gB + kk);
        __syncthreads();                          // prev iter reads done
        *(uint4*)(&As[sr][sk]) = av;
        *(uint4*)(&Bs[sr][sk]) = bv;
        __syncthreads();
        // A frag: lane holds F[m0+row][kk + kg*8 + j], row = lrow (+16)
        short8 a0 = *(const short8*)(&As[wr * 32      + lrow][kg * 8]);
        short8 a1 = *(const short8*)(&As[wr * 32 + 16 + lrow][kg * 8]);
        // B frag: lane holds lm[n0+col][kk + kg*8 + j], col = lrow (+16)
        short8 b0 = *(const short8*)(&Bs[wc * 32      + lrow][kg * 8]);
        short8 b1 = *(const short8*)(&Bs[wc * 32 + 16 + lrow][kg * 8]);
        acc[0][0] = __builtin_amdgcn_mfma_f32_16x16x32_bf16(a0, b0, acc[0][0], 0, 0, 0);
        acc[0][1] = __builtin_amdgcn_mfma_f32_16x16x32_bf16(a0, b1, acc[0][1], 0, 0, 0);
        acc[1][0] = __builtin_amdgcn_mfma_f32_16x16x32_bf16(a1, b0, acc[1][0], 0, 0, 0);
        acc[1][1] = __builtin_amdgcn_mfma_f32_16x16x32_bf16(a1, b1, acc[1][1], 0, 0, 0);
    }

    // Epilogue: C/D layout col = lane&15, row = (lane>>4)*4 + reg  [m89/m91]
    #pragma unroll
    for (int ni = 0; ni < 2; ++ni) {
        int cl = wc * 32 + ni * 16 + lrow;          // local col
        float tcx = tB[cl][0], tcy = tB[cl][1], tw = tB[cl][2], th = tB[cl][3];
        float tx0 = tcx - 0.5f * tw, ty0 = tcy - 0.5f * th;
        float tx1 = tcx + 0.5f * tw, ty1 = tcy + 0.5f * th;
        float areaT = (tx1 - tx0) * (ty1 - ty0);
        #pragma unroll
        for (int mi = 0; mi < 2; ++mi) {
            #pragma unroll
            for (int r = 0; r < 4; ++r) {
                int rl = wr * 32 + mi * 16 + kg * 4 + r;   // local row
                float pcx = pB[rl][0], pcy = pB[rl][1], pw = pB[rl][2], ph = pB[rl][3];
                float px0 = pcx - 0.5f * pw, py0 = pcy - 0.5f * ph;
                float px1 = pcx + 0.5f * pw, py1 = pcy + 0.5f * ph;
                float areaP = (px1 - px0) * (py1 - py0);
                float bbox = fabsf(pcx - tcx) + fabsf(pcy - tcy)
                           + fabsf(pw - tw)  + fabsf(ph - th);
                float ltx = fmaxf(px0, tx0), lty = fmaxf(py0, ty0);
                float rbx = fminf(px1, tx1), rby = fminf(py1, ty1);
                float iw = fmaxf(rbx - ltx, 0.0f), ih = fmaxf(rby - lty, 0.0f);
                float inter = iw * ih;
                float uni = areaP + areaT - inter;
                float iou = inter / uni;
                float ex0 = fminf(px0, tx0), ey0 = fminf(py0, ty0);
                float ex1 = fmaxf(px1, tx1), ey1 = fmaxf(py1, ty1);
                float areaE = fmaxf(ex1 - ex0, 0.0f) * fmaxf(ey1 - ey0, 0.0f);
                float giou = iou - (areaE - uni) / areaE;
                float cls = acc[mi][ni][r];
                out[(size_t)(m0 + rl) * BT + (n0 + cl)] =
                    5.0f * bbox + 2.0f * cls + 2.0f * (-giou);
            }
        }
    }
}

// ---------------------------------------------------------------------------
extern "C" void kernel_launch(void* const* d_in, const int* in_sizes, int n_in,
                              void* d_out, int out_size, void* d_ws, size_t ws_size,
                              hipStream_t stream) {
    const float* logits      = (const float*)d_in[0];   // [16,900,512]
    const float* pred_boxes  = (const float*)d_in[1];   // [16,900,4]
    const float* label_maps  = (const float*)d_in[2];   // [16,91,512]
    const float* boxes       = (const float*)d_in[3];   // [16,40,4]
    const int*   class_labels= (const int*)d_in[4];     // [16,40]
    float* out = (float*)d_out;                         // [16,900,640]

    __hip_bfloat16* F  = (__hip_bfloat16*)d_ws;                       // 14.7 MB
    __hip_bfloat16* lm = (__hip_bfloat16*)((char*)d_ws
                          + (size_t)BQ * CD * sizeof(__hip_bfloat16)); // +0.66 MB

    build_lm_kernel<<<BT, 256, 0, stream>>>(label_maps, class_labels, lm);
    build_focal_kernel<<<(BQ * CD / 4) / 256, 256, 0, stream>>>(logits, F);
    dim3 grid(BQ / 64, BT / 64);
    cost_gemm_kernel<<<grid, 256, 0, stream>>>(F, lm, pred_boxes, boxes, out);
}

// Round 3
// 120.442 us; speedup vs baseline: 1.1159x; 1.1159x over previous
//
#include <hip/hip_runtime.h>
#include <hip/hip_bf16.h>

// Problem constants (B=16, Q=900, C=512, T=40, L=91)
#define BQ   14400      // B*Q rows
#define BT   640        // B*T cols
#define CD   512        // class dim (K of the GEMM)
#define LD   91
#define TD   40

typedef __attribute__((ext_vector_type(8))) short short8;
typedef __attribute__((ext_vector_type(4))) float f32x4;

// ---------------------------------------------------------------------------
// Pass 1: build lm in MFMA-fragment-major layout, normalized, bf16.
//   Bf[nt][kb][lane][j] = lm_norm[nt*16 + (lane&15)][kb*32 + (lane>>4)*8 + j]
//   nt: 0..39 (16-col tiles of the output), kb: 0..15 (K blocks of 32)
// ---------------------------------------------------------------------------
__global__ __launch_bounds__(256) void build_lmfrag_kernel(
    const float* __restrict__ label_maps,   // [16][91][512]
    const int* __restrict__ class_labels,   // [640]
    __hip_bfloat16* __restrict__ Bf)        // [40][16][64][8]
{
    __shared__ float rows[16][512];         // 32 KB
    __shared__ float inv[16];
    int nt = blockIdx.x;
    int t  = threadIdx.x;

    // gather 16 label-map rows (coalesced float4 within each row)
    #pragma unroll
    for (int e = 0; e < 8; ++e) {
        int idx4 = t + e * 256;             // 0..2047 (float4 index)
        int r    = idx4 >> 7;               // 0..15
        int c4   = idx4 & 127;
        int j    = nt * 16 + r;
        int b    = j / TD;
        int cls  = class_labels[j];
        float4 v = *(const float4*)(label_maps + ((size_t)(b * LD + cls) * CD) + c4 * 4);
        *(float4*)(&rows[r][c4 * 4]) = v;
    }
    __syncthreads();

    // row sums -> inv
    int w = t >> 6, l = t & 63;
    #pragma unroll
    for (int q = 0; q < 4; ++q) {
        int r = w * 4 + q;
        float s = 0.f;
        #pragma unroll
        for (int e = 0; e < 8; ++e) s += rows[r][l + e * 64];
        #pragma unroll
        for (int off = 32; off >= 1; off >>= 1) s += __shfl_down(s, off, 64);
        if (l == 0) inv[r] = __builtin_amdgcn_rcpf(s);
    }
    __syncthreads();

    // write fragment-major chunks (contiguous 16B stores)
    #pragma unroll
    for (int e = 0; e < 4; ++e) {
        int sc = t + e * 256;               // chunk 0..1023
        int kb = sc >> 6;
        int ln = sc & 63;
        int o  = ln >> 4;                   // k-octet within kb
        int rr = ln & 15;                   // lm row within tile
        float scale = inv[rr];
        union { __hip_bfloat16 h[8]; uint4 u; } pk;
        #pragma unroll
        for (int j2 = 0; j2 < 8; ++j2)
            pk.h[j2] = __float2bfloat16(rows[rr][kb * 32 + o * 8 + j2] * scale);
        *(uint4*)((char*)Bf + ((size_t)nt * 1024 + sc) * 16) = pk.u;
    }
}

// ---------------------------------------------------------------------------
// focal term: pos - neg, via softplus identity (no eps needed for |x| < 18)
//   p = sigmoid(x); pos = .25*(1-p)^2*(-log p); neg = .75*p^2*(-log(1-p))
//   -log p = softplus(-x) = log(1+e^-x);  -log(1-p) = x + softplus(-x)
// ---------------------------------------------------------------------------
__device__ __forceinline__ float focal_term(float x)
{
    x = fminf(fmaxf(x, -18.0f), 18.0f);
    float q   = __expf(-x);                       // e^-x
    float s   = 1.0f + q;
    float p   = __builtin_amdgcn_rcpf(s);         // sigmoid(x)
    float spn = __logf(s);                        // softplus(-x)
    float omp = q * p;                            // 1 - p
    float pos = 0.25f * omp * omp * spn;
    float neg = 0.75f * p * p * (x + spn);
    return pos - neg;
}

// ---------------------------------------------------------------------------
// Fused main kernel: one block per 64-row M-tile, full N=640 in accumulators.
//   8 waves: wave (wr = w&1, wcg = w>>1), wave tile 32 rows x 160 cols.
//   A (focal) staged once in LDS (64x512 bf16, octet-XOR swizzled).
//   B frags loaded coalesced from fragment-major global (L2-resident).
//   Barrier-free k-loop; fused bbox/GIoU epilogue.
// ---------------------------------------------------------------------------
__global__ __launch_bounds__(512, 2) void fused_cost_kernel(
    const float* __restrict__ logits,       // [14400][512]
    const float* __restrict__ pred_boxes,   // [14400][4]
    const __hip_bfloat16* __restrict__ Bf,  // [40][16][64][8]
    const float* __restrict__ tboxes,       // [640][4]
    float* __restrict__ out)                // [14400][640]
{
    __shared__ __align__(16) short A[64][512];   // 64 KB, swizzled octets
    __shared__ float pB[64][4];
    __shared__ float tB[BT][4];

    int t  = threadIdx.x;
    int m0 = blockIdx.x * 64;

    // ---- stage boxes ----
    if (t < 64)  *(float4*)(&pB[t][0]) = *(const float4*)(pred_boxes + (size_t)(m0 + t) * 4);
    *(float4*)(&tB[t][0]) = *(const float4*)(tboxes + (size_t)t * 4);
    if (t < BT - 512) *(float4*)(&tB[512 + t][0]) = *(const float4*)(tboxes + (size_t)(512 + t) * 4);

    // ---- focal: logits -> bf16 A tile in LDS (swizzled) ----
    {
        int row = t >> 3;                   // 0..63
        int sl  = t & 7;
        int r7  = row & 7;
        const float* lp = logits + (size_t)(m0 + row) * CD + sl * 16;
        #pragma unroll
        for (int i = 0; i < 4; ++i) {
            union { float4 v4[4]; float f[16]; } xu;
            #pragma unroll
            for (int j = 0; j < 4; ++j) xu.v4[j] = *(const float4*)(lp + i * 128 + j * 4);
            union { __hip_bfloat16 h[16]; uint4 u[2]; } pk;
            #pragma unroll
            for (int k = 0; k < 16; ++k) pk.h[k] = __float2bfloat16(focal_term(xu.f[k]));
            int o0 = sl * 2 + i * 16;       // octet index (16B units)
            *(uint4*)(&A[row][(o0 ^ r7) * 8])       = pk.u[0];
            *(uint4*)(&A[row][((o0 + 1) ^ r7) * 8]) = pk.u[1];
        }
    }
    __syncthreads();

    // ---- barrier-free K loop ----
    int l    = t & 63;
    int w    = t >> 6;
    int wr   = w & 1;                       // row half: rows wr*32 .. +32
    int wcg  = w >> 1;                      // col group: cols wcg*160 .. +160
    int lrow = l & 15;
    int kg   = l >> 4;
    int r7a  = lrow & 7;                    // == arow&7 for both row frags
    int arow0 = wr * 32 + lrow;
    int arow1 = arow0 + 16;

    f32x4 acc[2][10] = {};
    const short8* bp = (const short8*)Bf + (size_t)wcg * 10240 + l;  // frag chunks

    #pragma unroll 2
    for (int kb = 0; kb < 16; ++kb) {
        short8 a0 = *(const short8*)(&A[arow0][((kb * 4 + kg) ^ r7a) * 8]);
        short8 a1 = *(const short8*)(&A[arow1][((kb * 4 + kg) ^ r7a) * 8]);
        short8 bfr[10];
        #pragma unroll
        for (int nf = 0; nf < 10; ++nf) bfr[nf] = bp[nf * 1024 + kb * 64];
        #pragma unroll
        for (int nf = 0; nf < 10; ++nf) {
            acc[0][nf] = __builtin_amdgcn_mfma_f32_16x16x32_bf16(a0, bfr[nf], acc[0][nf], 0, 0, 0);
            acc[1][nf] = __builtin_amdgcn_mfma_f32_16x16x32_bf16(a1, bfr[nf], acc[1][nf], 0, 0, 0);
        }
    }

    // ---- epilogue: hoist row params (8 rows/thread), loop cols ----
    float rp[8][9];
    #pragma unroll
    for (int rf = 0; rf < 2; ++rf) {
        #pragma unroll
        for (int r = 0; r < 4; ++r) {
            int rl = wr * 32 + rf * 16 + kg * 4 + r;
            float pcx = pB[rl][0], pcy = pB[rl][1], pw = pB[rl][2], ph = pB[rl][3];
            float* P = rp[rf * 4 + r];
            P[0] = pcx; P[1] = pcy; P[2] = pw; P[3] = ph;
            P[4] = pcx - 0.5f * pw;  // px0
            P[5] = pcy - 0.5f * ph;  // py0
            P[6] = pcx + 0.5f * pw;  // px1
            P[7] = pcy + 0.5f * ph;  // py1
            P[8] = pw * ph;          // areaP
        }
    }

    #pragma unroll
    for (int nf = 0; nf < 10; ++nf) {
        int cl = wcg * 160 + nf * 16 + lrow;
        float tcx = tB[cl][0], tcy = tB[cl][1], tw = tB[cl][2], th = tB[cl][3];
        float tx0 = tcx - 0.5f * tw, ty0 = tcy - 0.5f * th;
        float tx1 = tcx + 0.5f * tw, ty1 = tcy + 0.5f * th;
        float areaT = tw * th;
        #pragma unroll
        for (int rf = 0; rf < 2; ++rf) {
            #pragma unroll
            for (int r = 0; r < 4; ++r) {
                const float* P = rp[rf * 4 + r];
                float bbox = fabsf(P[0] - tcx) + fabsf(P[1] - tcy)
                           + fabsf(P[2] - tw)  + fabsf(P[3] - th);
                float iw = fminf(P[6], tx1) - fmaxf(P[4], tx0);
                float ih = fminf(P[7], ty1) - fmaxf(P[5], ty0);
                iw = fmaxf(iw, 0.0f); ih = fmaxf(ih, 0.0f);
                float inter = iw * ih;
                float uni   = P[8] + areaT - inter;
                float ew = fmaxf(P[6], tx1) - fminf(P[4], tx0);
                float eh = fmaxf(P[7], ty1) - fminf(P[5], ty0);
                float areaE = ew * eh;
                float iou  = inter * __builtin_amdgcn_rcpf(uni);
                float gpen = (areaE - uni) * __builtin_amdgcn_rcpf(areaE);
                float giou = iou - gpen;
                float cls  = acc[rf][nf][r];
                int rl = wr * 32 + rf * 16 + kg * 4 + r;
                out[(size_t)(m0 + rl) * BT + cl] = 5.0f * bbox + 2.0f * cls - 2.0f * giou;
            }
        }
    }
}

// ---------------------------------------------------------------------------
extern "C" void kernel_launch(void* const* d_in, const int* in_sizes, int n_in,
                              void* d_out, int out_size, void* d_ws, size_t ws_size,
                              hipStream_t stream) {
    const float* logits       = (const float*)d_in[0];   // [16,900,512]
    const float* pred_boxes   = (const float*)d_in[1];   // [16,900,4]
    const float* label_maps   = (const float*)d_in[2];   // [16,91,512]
    const float* boxes        = (const float*)d_in[3];   // [16,40,4]
    const int*   class_labels = (const int*)d_in[4];     // [16,40]
    float* out = (float*)d_out;                          // [16,900,640]

    __hip_bfloat16* Bf = (__hip_bfloat16*)d_ws;          // 655 KB frag-major lm

    build_lmfrag_kernel<<<40, 256, 0, stream>>>(label_maps, class_labels, Bf);
    fused_cost_kernel<<<BQ / 64, 512, 0, stream>>>(logits, pred_boxes, Bf, boxes, out);
}

// Round 4
// 109.351 us; speedup vs baseline: 1.2291x; 1.1014x over previous
//
#include <hip/hip_runtime.h>
#include <hip/hip_bf16.h>

// Problem constants (B=16, Q=900, C=512, T=40, L=91)
#define BQ   14400      // B*Q rows
#define BT   640        // B*T cols
#define CD   512        // class dim (K of the GEMM)
#define LD   91
#define TD   40

typedef __attribute__((ext_vector_type(8))) short short8;
typedef __attribute__((ext_vector_type(4))) float f32x4;

// ---------------------------------------------------------------------------
// Pass 1: build lm normalized bf16 in wave-major MFMA-fragment layout:
//   Bf[w][kb][nf][lane][j],  w=0..7 (80-col wave slice), kb=0..15 (K/32),
//   nf=0..4 (16-col frag).  Global col = w*80 + nf*16 + (lane&15),
//   k = kb*32 + (lane>>4)*8 + j.
// ---------------------------------------------------------------------------
__global__ __launch_bounds__(256) void build_lmfrag_kernel(
    const float* __restrict__ label_maps,   // [16][91][512]
    const int* __restrict__ class_labels,   // [640]
    __hip_bfloat16* __restrict__ Bf)        // [8][16][5][64][8]
{
    __shared__ float rows[16][512];         // 32 KB
    __shared__ float inv[16];
    int nt = blockIdx.x;                    // 16-col tile, 0..39
    int t  = threadIdx.x;

    // gather 16 label-map rows (coalesced float4 within each row)
    #pragma unroll
    for (int e = 0; e < 8; ++e) {
        int idx4 = t + e * 256;             // float4 index 0..2047
        int r    = idx4 >> 7;
        int c4   = idx4 & 127;
        int j    = nt * 16 + r;
        int b    = j / TD;
        int cls  = class_labels[j];
        float4 v = *(const float4*)(label_maps + ((size_t)(b * LD + cls) * CD) + c4 * 4);
        *(float4*)(&rows[r][c4 * 4]) = v;
    }
    __syncthreads();

    int w = t >> 6, l = t & 63;
    #pragma unroll
    for (int q = 0; q < 4; ++q) {
        int r = w * 4 + q;
        float s = 0.f;
        #pragma unroll
        for (int e = 0; e < 8; ++e) s += rows[r][l + e * 64];
        #pragma unroll
        for (int off = 32; off >= 1; off >>= 1) s += __shfl_down(s, off, 64);
        if (l == 0) inv[r] = __builtin_amdgcn_rcpf(s);
    }
    __syncthreads();

    int w5 = nt / 5, nf5 = nt % 5;
    #pragma unroll
    for (int e = 0; e < 4; ++e) {
        int sc = t + e * 256;               // 0..1023
        int kb = sc >> 6;
        int ln = sc & 63;
        int o  = ln >> 4;
        int rr = ln & 15;
        float scale = inv[rr];
        union { __hip_bfloat16 h[8]; uint4 u; } pk;
        #pragma unroll
        for (int j2 = 0; j2 < 8; ++j2)
            pk.h[j2] = __float2bfloat16(rows[rr][kb * 32 + o * 8 + j2] * scale);
        size_t chunk = (size_t)(w5 * 16 + kb) * 5 + nf5;
        *(uint4*)((char*)Bf + (chunk * 64 + ln) * 16) = pk.u;
    }
}

// ---------------------------------------------------------------------------
// focal term: pos - neg via softplus identity (exact; no eps needed |x|<18)
// ---------------------------------------------------------------------------
__device__ __forceinline__ float focal_term(float x)
{
    x = fminf(fmaxf(x, -18.0f), 18.0f);
    float q   = __expf(-x);                       // e^-x
    float s   = 1.0f + q;
    float p   = __builtin_amdgcn_rcpf(s);         // sigmoid(x)
    float spn = __logf(s);                        // softplus(-x) = -log p
    float omp = q * p;                            // 1 - p
    float pos = 0.25f * omp * omp * spn;
    float neg = 0.75f * p * p * (x + spn);
    return pos - neg;
}

// ---------------------------------------------------------------------------
// Fused main kernel. Grid 225, 512 threads (8 waves).
//   Wave w owns cols [w*80, w*80+80) x all 64 rows: acc[4 rf][5 nf] (80 VGPR).
//   B deduplicated: each byte of Bf read once per block (640 KB/CU).
//   3-buffer 2-deep register prefetch of B; first 2 kb issued before focal.
//   A (focal) staged once in LDS (64x512 bf16, octet-XOR swizzled).
// ---------------------------------------------------------------------------
__global__ __launch_bounds__(512, 2) void fused_cost_kernel(
    const float* __restrict__ logits,       // [14400][512]
    const float* __restrict__ pred_boxes,   // [14400][4]
    const __hip_bfloat16* __restrict__ Bf,  // [8][16][5][64][8]
    const float* __restrict__ tboxes,       // [640][4]
    float* __restrict__ out)                // [14400][640]
{
    __shared__ __align__(16) short A[64][512];   // 64 KB, swizzled octets
    __shared__ float pB[64][4];

    int t  = threadIdx.x;
    int m0 = blockIdx.x * 64;
    int l    = t & 63;
    int w    = t >> 6;                      // 0..7
    int lrow = l & 15;
    int kg   = l >> 4;
    int r7a  = lrow & 7;

    // per-wave, per-lane B base (short8 units); frag (kb,nf) at +(kb*5+nf)*64
    const short8* bw = (const short8*)Bf + (size_t)w * 80 * 64 + l;

    short8 b0[5], b1[5], b2[5];
    #pragma unroll
    for (int nf = 0; nf < 5; ++nf) b0[nf] = bw[(0 * 5 + nf) * 64];
    #pragma unroll
    for (int nf = 0; nf < 5; ++nf) b1[nf] = bw[(1 * 5 + nf) * 64];

    if (t < 64) *(float4*)(&pB[t][0]) = *(const float4*)(pred_boxes + (size_t)(m0 + t) * 4);

    // ---- focal: logits -> bf16 A tile in LDS (swizzled), overlaps B latency
    {
        int row = t >> 3;                   // 0..63
        int sl  = t & 7;
        int r7  = row & 7;
        const float* lp = logits + (size_t)(m0 + row) * CD + sl * 16;
        #pragma unroll
        for (int i = 0; i < 4; ++i) {
            union { float4 v4[4]; float f[16]; } xu;
            #pragma unroll
            for (int j = 0; j < 4; ++j) xu.v4[j] = *(const float4*)(lp + i * 128 + j * 4);
            union { __hip_bfloat16 h[16]; uint4 u[2]; } pk;
            #pragma unroll
            for (int k = 0; k < 16; ++k) pk.h[k] = __float2bfloat16(focal_term(xu.f[k]));
            int o0 = sl * 2 + i * 16;       // octet index (16B units)
            *(uint4*)(&A[row][(o0 ^ r7) * 8])       = pk.u[0];
            *(uint4*)(&A[row][((o0 + 1) ^ r7) * 8]) = pk.u[1];
        }
    }
    __syncthreads();

    // ---- K loop: fully unrolled, 3-buffer rotation, 2-deep prefetch ----
    f32x4 acc[4][5] = {};
    #pragma unroll
    for (int kb = 0; kb < 16; ++kb) {
        short8* const bufs[3] = { b0, b1, b2 };      // const-indexed after unroll
        if (kb < 14) {
            short8* nb = bufs[(kb + 2) % 3];
            #pragma unroll
            for (int nf = 0; nf < 5; ++nf) nb[nf] = bw[((kb + 2) * 5 + nf) * 64];
        }
        const short8* cb = bufs[kb % 3];
        #pragma unroll
        for (int rf = 0; rf < 4; ++rf) {
            short8 a = *(const short8*)(&A[rf * 16 + lrow][((kb * 4 + kg) ^ r7a) * 8]);
            #pragma unroll
            for (int nf = 0; nf < 5; ++nf)
                acc[rf][nf] = __builtin_amdgcn_mfma_f32_16x16x32_bf16(a, cb[nf], acc[rf][nf], 0, 0, 0);
        }
    }

    // ---- epilogue: hoist derived col params (5), loop row frags ----
    float tc[5][8];   // tcx,tcy,tw,th, tx0,ty0,tx1,ty1
    #pragma unroll
    for (int nf = 0; nf < 5; ++nf) {
        int cl = w * 80 + nf * 16 + lrow;
        float4 tb = *(const float4*)(tboxes + (size_t)cl * 4);
        tc[nf][0] = tb.x; tc[nf][1] = tb.y; tc[nf][2] = tb.z; tc[nf][3] = tb.w;
        tc[nf][4] = tb.x - 0.5f * tb.z;
        tc[nf][5] = tb.y - 0.5f * tb.w;
        tc[nf][6] = tb.x + 0.5f * tb.z;
        tc[nf][7] = tb.y + 0.5f * tb.w;
    }

    #pragma unroll
    for (int rf = 0; rf < 4; ++rf) {
        #pragma unroll
        for (int r = 0; r < 4; ++r) {
            int rl = rf * 16 + kg * 4 + r;
            float4 pb = *(const float4*)(&pB[rl][0]);
            float px0 = pb.x - 0.5f * pb.z, py0 = pb.y - 0.5f * pb.w;
            float px1 = pb.x + 0.5f * pb.z, py1 = pb.y + 0.5f * pb.w;
            float areaP = pb.z * pb.w;
            size_t orow = (size_t)(m0 + rl) * BT + w * 80 + lrow;
            #pragma unroll
            for (int nf = 0; nf < 5; ++nf) {
                const float* T = tc[nf];
                float bbox = fabsf(pb.x - T[0]) + fabsf(pb.y - T[1])
                           + fabsf(pb.z - T[2]) + fabsf(pb.w - T[3]);
                float iw = fminf(px1, T[6]) - fmaxf(px0, T[4]);
                float ih = fminf(py1, T[7]) - fmaxf(py0, T[5]);
                iw = fmaxf(iw, 0.0f); ih = fmaxf(ih, 0.0f);
                float inter = iw * ih;
                float uni   = areaP + T[2] * T[3] - inter;
                float ew = fmaxf(px1, T[6]) - fminf(px0, T[4]);
                float eh = fmaxf(py1, T[7]) - fminf(py0, T[5]);
                float areaE = ew * eh;
                float iou  = inter * __builtin_amdgcn_rcpf(uni);
                float gpen = (areaE - uni) * __builtin_amdgcn_rcpf(areaE);
                float giou = iou - gpen;
                float cls  = acc[rf][nf][r];
                out[orow + nf * 16] = 5.0f * bbox + 2.0f * cls - 2.0f * giou;
            }
        }
    }
}

// ---------------------------------------------------------------------------
extern "C" void kernel_launch(void* const* d_in, const int* in_sizes, int n_in,
                              void* d_out, int out_size, void* d_ws, size_t ws_size,
                              hipStream_t stream) {
    const float* logits       = (const float*)d_in[0];   // [16,900,512]
    const float* pred_boxes   = (const float*)d_in[1];   // [16,900,4]
    const float* label_maps   = (const float*)d_in[2];   // [16,91,512]
    const float* boxes        = (const float*)d_in[3];   // [16,40,4]
    const int*   class_labels = (const int*)d_in[4];     // [16,40]
    float* out = (float*)d_out;                          // [16,900,640]

    __hip_bfloat16* Bf = (__hip_bfloat16*)d_ws;          // 655 KB frag-major lm

    build_lmfrag_kernel<<<40, 256, 0, stream>>>(label_maps, class_labels, Bf);
    fused_cost_kernel<<<BQ / 64, 512, 0, stream>>>(logits, pred_boxes, Bf, boxes, out);
}